// Round 10
// baseline (82.832 us; speedup 1.0000x reference)
//
#include <hip/hip_runtime.h>
#include <hip/hip_fp16.h>

#define HW_ (768 * 1024)
#define W_ 1024
#define DC 0.867f
#define DD 0.005f
#define DZ 0.0001f

#define SEG_STRIDE 260   // halfs per (batch,channel) segment in LDS (256 px + 4 pad)

// ---------------- shared group math (ACCUMULATES into s_loss/s_cnt) -------
__device__ __forceinline__ void vn_group_math(
    const float G1[3], const float G2[3], const float G3[3],
    const float P1[3], const float P2[3], const float P3[3],
    float& s_loss, float& s_cnt)
{
    float d0[3], d1[3], d2[3];
    #pragma unroll
    for (int c = 0; c < 3; c++) {
        d0[c] = G2[c] - G1[c];
        d1[c] = G3[c] - G1[c];
        d2[c] = G3[c] - G2[c];
    }

    float e00 = d0[0]*d0[0] + d0[1]*d0[1] + d0[2]*d0[2];
    float e11 = d1[0]*d1[0] + d1[1]*d1[1] + d1[2]*d1[2];
    float e22 = d2[0]*d2[0] + d2[1]*d2[1] + d2[2]*d2[2];
    float e01 = d0[0]*d1[0] + d0[1]*d1[1] + d0[2]*d1[2];
    float e02 = d0[0]*d2[0] + d0[1]*d2[1] + d0[2]*d2[2];
    float e12 = d1[0]*d2[0] + d1[1]*d2[1] + d1[2]*d2[2];
    float s0 = sqrtf(e00), s1 = sqrtf(e11), s2 = sqrtf(e22);

    int cc = 0;
    {
        float ne;
        ne = e00 / (s0*s0 + 1e-8f); cc += (ne > DC) || (ne < -DC);
        ne = e11 / (s1*s1 + 1e-8f); cc += (ne > DC) || (ne < -DC);
        ne = e22 / (s2*s2 + 1e-8f); cc += (ne > DC) || (ne < -DC);
        ne = e01 / (s0*s1 + 1e-8f); cc += 2 * ((ne > DC) || (ne < -DC));
        ne = e02 / (s0*s2 + 1e-8f); cc += 2 * ((ne > DC) || (ne < -DC));
        ne = e12 / (s1*s2 + 1e-8f); cc += 2 * ((ne > DC) || (ne < -DC));
    }
    bool mask_cos = cc > 3;
    bool mask_pad = (G1[2] > DZ) && (G2[2] > DZ) && (G3[2] > DZ);
    bool mx = (fabsf(d0[0]) < DD) || (fabsf(d1[0]) < DD) || (fabsf(d2[0]) < DD);
    bool my = (fabsf(d0[1]) < DD) || (fabsf(d1[1]) < DD) || (fabsf(d2[1]) < DD);
    bool mz = (fabsf(d0[2]) < DD) || (fabsf(d1[2]) < DD) || (fabsf(d2[2]) < DD);
    bool mask = mask_pad && !((mx && my && mz) || mask_cos);

    if (mask) {
        float n0 = d0[1]*d1[2] - d0[2]*d1[1];
        float n1 = d0[2]*d1[0] - d0[0]*d1[2];
        float n2 = d0[0]*d1[1] - d0[1]*d1[0];
        float nn = sqrtf(n0*n0 + n1*n1 + n2*n2);
        if (nn == 0.f) nn = 0.01f;

        // bug-faithful zmask broadcast: mask indexed by POINT, applied on CHANNEL
        bool zm[3] = { P1[2] == 0.f, P2[2] == 0.f, P3[2] == 0.f };
        float Q1[3], Q2[3], Q3[3];
        #pragma unroll
        for (int c = 0; c < 3; c++) {
            Q1[c] = zm[c] ? 0.0001f : P1[c];
            Q2[c] = zm[c] ? 0.0001f : P2[c];
            Q3[c] = zm[c] ? 0.0001f : P3[c];
        }
        float q0[3], q1[3];
        #pragma unroll
        for (int c = 0; c < 3; c++) {
            q0[c] = Q2[c] - Q1[c];
            q1[c] = Q3[c] - Q1[c];
        }
        float m0 = q0[1]*q1[2] - q0[2]*q1[1];
        float m1 = q0[2]*q1[0] - q0[0]*q1[2];
        float m2 = q0[0]*q1[1] - q0[1]*q1[0];
        float mn = sqrtf(m0*m0 + m1*m1 + m2*m2);
        if (mn == 0.f) mn = 0.01f;

        s_loss += fabsf(n0/nn - m0/mn) + fabsf(n1/nn - m1/mn) + fabsf(n2/nn - m2/mn);
        s_cnt  += 1.f;
    }
}

__device__ __forceinline__ void vn_reduce_store(float s_loss, float s_cnt, double* acc)
{
    #pragma unroll
    for (int off = 32; off > 0; off >>= 1) {
        s_loss += __shfl_down(s_loss, off);
        s_cnt  += __shfl_down(s_cnt,  off);
    }
    __shared__ float ls[4], lc[4];
    int lane = threadIdx.x & 63;
    int wid  = threadIdx.x >> 6;
    if (lane == 0) { ls[wid] = s_loss; lc[wid] = s_cnt; }
    __syncthreads();
    if (threadIdx.x == 0) {
        float tl = ls[0] + ls[1] + ls[2] + ls[3];
        float tc = lc[0] + lc[1] + lc[2] + lc[3];
        atomicAdd(acc,     (double)tl);
        atomicAdd(acc + 1, (double)tc);
    }
}

// ---------------- mark touched pixels + init accumulators -----------------
// Byte mask, plain stores (races benign). Block 0 thread 0 zeroes acc/done
// (this dispatch completes before gather starts -> visible).
__global__ __launch_bounds__(256) void vn_mark8(
    const int* __restrict__ p1x, const int* __restrict__ p1y,
    const int* __restrict__ p2x, const int* __restrict__ p2y,
    const int* __restrict__ p3x, const int* __restrict__ p3y,
    int G, unsigned char* __restrict__ mask8,
    double* __restrict__ acc, unsigned int* __restrict__ done)
{
    int g = blockIdx.x * 256 + threadIdx.x;
    if (blockIdx.x == 0 && threadIdx.x == 0) {
        acc[0] = 0.0;
        acc[1] = 0.0;
        *done  = 0u;
    }
    if (g >= G) return;
    mask8[p1y[g] * W_ + p1x[g]] = 1;
    mask8[p2y[g] * W_ + p2x[g]] = 1;
    mask8[p3y[g] * W_ + p3x[g]] = 1;
}

// ---------------- pack via LDS transpose, 256px tile, TOUCHED ONLY --------
// Phase 1: float4 coalesced plane reads (1KB/wave-inst) -> f16 LDS stage.
// Phase 2: assemble 16B records; store only touched pixels (~36%).
// SELF-CLEANING: after reading its mask words this block zeroes them, so no
// per-call memset is needed. Correct from ANY prior mask state: a stale-set
// bit only causes a harmless extra record write; mark always sets every bit
// the gather will need this call.
// rec[pix*8 + b] = uint4{ h2(gt0,gt1), h2(gt2,pr0), h2(pr1,pr2), 0 }
__global__ __launch_bounds__(256) void vn_pack_m(
    const float* __restrict__ gt, const float* __restrict__ pred,
    unsigned char* __restrict__ mask8, uint4* __restrict__ rec)
{
    __shared__ __half lh[48 * SEG_STRIDE];       // 24.96 KB
    __shared__ unsigned char lmask[256];

    size_t px_base = (size_t)blockIdx.x * 256;
    int t = threadIdx.x;
    int w = t >> 6, l = t & 63;

    if (t < 64) {
        unsigned int* gm = (unsigned int*)(mask8 + px_base);
        unsigned int m = gm[t];
        ((unsigned int*)lmask)[t] = m;
        gm[t] = 0u;                       // self-clean for next call
    }

    // phase 1: each wave loads 12 segments; one 1KB contiguous read per inst
    #pragma unroll
    for (int k = 0; k < 12; k++) {
        int s = w * 12 + k;              // s = b*6 + c
        int b = s / 6, c = s % 6;
        const float* src = (c < 3)
            ? gt   + ((size_t)b * 3 + c)       * HW_ + px_base
            : pred + ((size_t)b * 3 + (c - 3)) * HW_ + px_base;
        float4 v = *(const float4*)(src + l * 4);
        __half2 v01 = __floats2half2_rn(v.x, v.y);
        __half2 v23 = __floats2half2_rn(v.z, v.w);
        uint2 pk;
        pk.x = *(unsigned int*)&v01;
        pk.y = *(unsigned int*)&v23;
        *(uint2*)(&lh[(size_t)s * SEG_STRIDE + l * 4]) = pk;
    }

    __syncthreads();

    // phase 2: 8 records/thread; predicated 1KB-contiguous wave stores
    int b  = t & 7;
    int c6 = b * 6;
    uint4* out = rec + px_base * 8;
    #pragma unroll
    for (int r = 0; r < 8; r++) {
        int j    = t + r * 256;
        int i_px = j >> 3;               // [0,256)
        if (lmask[i_px]) {
            uint4 o;
            __half2* hh = (__half2*)&o;
            hh[0] = __halves2half2(lh[(c6 + 0) * SEG_STRIDE + i_px],
                                   lh[(c6 + 1) * SEG_STRIDE + i_px]);
            hh[1] = __halves2half2(lh[(c6 + 2) * SEG_STRIDE + i_px],
                                   lh[(c6 + 3) * SEG_STRIDE + i_px]);
            hh[2] = __halves2half2(lh[(c6 + 4) * SEG_STRIDE + i_px],
                                   lh[(c6 + 5) * SEG_STRIDE + i_px]);
            o.w = 0u;
            out[j] = o;
        }
    }
}

__device__ __forceinline__ void unpack_rec(uint4 r, float G[3], float P[3])
{
    __half2 a = *(__half2*)&r.x;
    __half2 b = *(__half2*)&r.y;
    __half2 c = *(__half2*)&r.z;
    G[0] = __low2float(a);  G[1] = __high2float(a);
    G[2] = __low2float(b);  P[0] = __high2float(b);
    P[1] = __low2float(c);  P[2] = __high2float(c);
}

// ---------------- gather + fused final (last-block-done) -------------------
__global__ __launch_bounds__(256) void vn_gather_h(
    const uint4* __restrict__ rec,
    const int* __restrict__ p1x, const int* __restrict__ p1y,
    const int* __restrict__ p2x, const int* __restrict__ p2y,
    const int* __restrict__ p3x, const int* __restrict__ p3y,
    int G, double* __restrict__ acc,
    unsigned int* __restrict__ done, int nblocks, float* __restrict__ outp)
{
    int t = blockIdx.x * 256 + threadIdx.x;
    int g = t >> 1;
    int h = (t & 1) * 4;          // batches [h, h+4)

    float s_loss = 0.f, s_cnt = 0.f;

    if (g < G) {
        size_t q1 = ((size_t)(p1y[g] * W_ + p1x[g])) * 8 + h;
        size_t q2 = ((size_t)(p2y[g] * W_ + p2x[g])) * 8 + h;
        size_t q3 = ((size_t)(p3y[g] * W_ + p3x[g])) * 8 + h;

        uint4 r1[4], r2[4], r3[4];
        #pragma unroll
        for (int j = 0; j < 4; j++) r1[j] = rec[q1 + j];
        #pragma unroll
        for (int j = 0; j < 4; j++) r2[j] = rec[q2 + j];
        #pragma unroll
        for (int j = 0; j < 4; j++) r3[j] = rec[q3 + j];

        #pragma unroll
        for (int j = 0; j < 4; j++) {
            float G1[3], P1[3], G2[3], P2[3], G3[3], P3[3];
            unpack_rec(r1[j], G1, P1);
            unpack_rec(r2[j], G2, P2);
            unpack_rec(r3[j], G3, P3);
            vn_group_math(G1, G2, G3, P1, P2, P3, s_loss, s_cnt);
        }
    }

    vn_reduce_store(s_loss, s_cnt, acc);

    if (threadIdx.x == 0) {
        __threadfence();
        unsigned int v = atomicAdd(done, 1u);
        if (v == (unsigned int)(nblocks - 1)) {
            float s = (float)atomicAdd(acc,     0.0);
            float c = (float)atomicAdd(acc + 1, 0.0);
            outp[0] = s / fmaxf(c, 1.0f);
        }
    }
}

// ---------------- fallback: direct gather from plane-major (f32 exact) -----
__global__ __launch_bounds__(256) void vn_main(
    const float* __restrict__ gt, const float* __restrict__ pred,
    const int* __restrict__ p1x, const int* __restrict__ p1y,
    const int* __restrict__ p2x, const int* __restrict__ p2y,
    const int* __restrict__ p3x, const int* __restrict__ p3y,
    int G, double* __restrict__ acc)
{
    int g = blockIdx.x * 256 + threadIdx.x;
    int b = blockIdx.y;

    float s_loss = 0.f, s_cnt = 0.f;

    if (g < G) {
        int o1 = p1y[g] * W_ + p1x[g];
        int o2 = p2y[g] * W_ + p2x[g];
        int o3 = p3y[g] * W_ + p3x[g];
        const float* gb = gt   + (size_t)b * 3 * HW_;
        const float* pb = pred + (size_t)b * 3 * HW_;

        float G1[3], G2[3], G3[3], P1[3], P2[3], P3[3];
        #pragma unroll
        for (int c = 0; c < 3; c++) {
            G1[c] = gb[c * HW_ + o1];
            G2[c] = gb[c * HW_ + o2];
            G3[c] = gb[c * HW_ + o3];
            P1[c] = pb[c * HW_ + o1];
            P2[c] = pb[c * HW_ + o2];
            P3[c] = pb[c * HW_ + o3];
        }
        vn_group_math(G1, G2, G3, P1, P2, P3, s_loss, s_cnt);
    }

    vn_reduce_store(s_loss, s_cnt, acc);
}

__global__ void vn_final(const double* __restrict__ acc, float* __restrict__ out)
{
    float s = (float)acc[0];
    float c = (float)acc[1];
    out[0] = s / fmaxf(c, 1.0f);
}

extern "C" void kernel_launch(void* const* d_in, const int* in_sizes, int n_in,
                              void* d_out, int out_size, void* d_ws, size_t ws_size,
                              hipStream_t stream) {
    const float* gt   = (const float*)d_in[0];
    const float* pred = (const float*)d_in[1];
    const int* p1x = (const int*)d_in[2];
    const int* p1y = (const int*)d_in[3];
    const int* p2x = (const int*)d_in[4];
    const int* p2y = (const int*)d_in[5];
    const int* p3x = (const int*)d_in[6];
    const int* p3y = (const int*)d_in[7];

    int G = in_sizes[2];
    int B = in_sizes[0] / (3 * HW_);

    // ws layout: [0..16) acc doubles, [16..20) done counter,
    //            [256..) byte mask (768KB), [1MB..) records (100MB)
    double*       acc  = (double*)d_ws;
    unsigned int* done = (unsigned int*)((char*)d_ws + 16);

    size_t mask_off   = 256;
    size_t rec_off    = 1 << 20;
    size_t rec_bytes  = (size_t)HW_ * 8 * sizeof(uint4);      // 16B per (pixel,batch)
    size_t need = rec_off + rec_bytes;

    if (B == 8 && ws_size >= need) {
        unsigned char* mask8 = (unsigned char*)d_ws + mask_off;
        uint4*         rec   = (uint4*)((char*)d_ws + rec_off);

        vn_mark8<<<(G + 255) / 256, 256, 0, stream>>>(
            p1x, p1y, p2x, p2y, p3x, p3y, G, mask8, acc, done);
        vn_pack_m<<<HW_ / 256, 256, 0, stream>>>(gt, pred, mask8, rec);
        int nthreads = G * 2;                                 // 2 threads per group
        int nblocks  = (nthreads + 255) / 256;
        vn_gather_h<<<nblocks, 256, 0, stream>>>(
            rec, p1x, p1y, p2x, p2y, p3x, p3y, G, acc, done, nblocks, (float*)d_out);
    } else {
        hipMemsetAsync(acc, 0, 2 * sizeof(double), stream);
        dim3 grid((G + 255) / 256, B);
        vn_main<<<grid, 256, 0, stream>>>(gt, pred, p1x, p1y, p2x, p2y, p3x, p3y, G, acc);
        vn_final<<<1, 1, 0, stream>>>(acc, (float*)d_out);
    }
}

// Round 11
// 78.154 us; speedup vs baseline: 1.0598x; 1.0598x over previous
//
#include <hip/hip_runtime.h>
#include <hip/hip_fp16.h>

#define HW_ (768 * 1024)
#define W_ 1024
#define DC 0.867f
#define DD 0.005f
#define DZ 0.0001f

#define SEG_STRIDE 260   // halfs per (batch,channel) segment in LDS (256 px + 4 pad)

// ---------------- shared group math (ACCUMULATES into s_loss/s_cnt) -------
__device__ __forceinline__ void vn_group_math(
    const float G1[3], const float G2[3], const float G3[3],
    const float P1[3], const float P2[3], const float P3[3],
    float& s_loss, float& s_cnt)
{
    float d0[3], d1[3], d2[3];
    #pragma unroll
    for (int c = 0; c < 3; c++) {
        d0[c] = G2[c] - G1[c];
        d1[c] = G3[c] - G1[c];
        d2[c] = G3[c] - G2[c];
    }

    float e00 = d0[0]*d0[0] + d0[1]*d0[1] + d0[2]*d0[2];
    float e11 = d1[0]*d1[0] + d1[1]*d1[1] + d1[2]*d1[2];
    float e22 = d2[0]*d2[0] + d2[1]*d2[1] + d2[2]*d2[2];
    float e01 = d0[0]*d1[0] + d0[1]*d1[1] + d0[2]*d1[2];
    float e02 = d0[0]*d2[0] + d0[1]*d2[1] + d0[2]*d2[2];
    float e12 = d1[0]*d2[0] + d1[1]*d2[1] + d1[2]*d2[2];
    float s0 = sqrtf(e00), s1 = sqrtf(e11), s2 = sqrtf(e22);

    int cc = 0;
    {
        float ne;
        ne = e00 / (s0*s0 + 1e-8f); cc += (ne > DC) || (ne < -DC);
        ne = e11 / (s1*s1 + 1e-8f); cc += (ne > DC) || (ne < -DC);
        ne = e22 / (s2*s2 + 1e-8f); cc += (ne > DC) || (ne < -DC);
        ne = e01 / (s0*s1 + 1e-8f); cc += 2 * ((ne > DC) || (ne < -DC));
        ne = e02 / (s0*s2 + 1e-8f); cc += 2 * ((ne > DC) || (ne < -DC));
        ne = e12 / (s1*s2 + 1e-8f); cc += 2 * ((ne > DC) || (ne < -DC));
    }
    bool mask_cos = cc > 3;
    bool mask_pad = (G1[2] > DZ) && (G2[2] > DZ) && (G3[2] > DZ);
    bool mx = (fabsf(d0[0]) < DD) || (fabsf(d1[0]) < DD) || (fabsf(d2[0]) < DD);
    bool my = (fabsf(d0[1]) < DD) || (fabsf(d1[1]) < DD) || (fabsf(d2[1]) < DD);
    bool mz = (fabsf(d0[2]) < DD) || (fabsf(d1[2]) < DD) || (fabsf(d2[2]) < DD);
    bool mask = mask_pad && !((mx && my && mz) || mask_cos);

    if (mask) {
        float n0 = d0[1]*d1[2] - d0[2]*d1[1];
        float n1 = d0[2]*d1[0] - d0[0]*d1[2];
        float n2 = d0[0]*d1[1] - d0[1]*d1[0];
        float nn = sqrtf(n0*n0 + n1*n1 + n2*n2);
        if (nn == 0.f) nn = 0.01f;

        // bug-faithful zmask broadcast: mask indexed by POINT, applied on CHANNEL
        bool zm[3] = { P1[2] == 0.f, P2[2] == 0.f, P3[2] == 0.f };
        float Q1[3], Q2[3], Q3[3];
        #pragma unroll
        for (int c = 0; c < 3; c++) {
            Q1[c] = zm[c] ? 0.0001f : P1[c];
            Q2[c] = zm[c] ? 0.0001f : P2[c];
            Q3[c] = zm[c] ? 0.0001f : P3[c];
        }
        float q0[3], q1[3];
        #pragma unroll
        for (int c = 0; c < 3; c++) {
            q0[c] = Q2[c] - Q1[c];
            q1[c] = Q3[c] - Q1[c];
        }
        float m0 = q0[1]*q1[2] - q0[2]*q1[1];
        float m1 = q0[2]*q1[0] - q0[0]*q1[2];
        float m2 = q0[0]*q1[1] - q0[1]*q1[0];
        float mn = sqrtf(m0*m0 + m1*m1 + m2*m2);
        if (mn == 0.f) mn = 0.01f;

        s_loss += fabsf(n0/nn - m0/mn) + fabsf(n1/nn - m1/mn) + fabsf(n2/nn - m2/mn);
        s_cnt  += 1.f;
    }
}

__device__ __forceinline__ void vn_reduce_store(float s_loss, float s_cnt, double* acc)
{
    #pragma unroll
    for (int off = 32; off > 0; off >>= 1) {
        s_loss += __shfl_down(s_loss, off);
        s_cnt  += __shfl_down(s_cnt,  off);
    }
    __shared__ float ls[4], lc[4];
    int lane = threadIdx.x & 63;
    int wid  = threadIdx.x >> 6;
    if (lane == 0) { ls[wid] = s_loss; lc[wid] = s_cnt; }
    __syncthreads();
    if (threadIdx.x == 0) {
        float tl = ls[0] + ls[1] + ls[2] + ls[3];
        float tc = lc[0] + lc[1] + lc[2] + lc[3];
        atomicAdd(acc,     (double)tl);
        atomicAdd(acc + 1, (double)tc);
    }
}

// ---------------- mark touched pixels + zero accumulators -----------------
// Byte mask, plain stores (races benign). Block 0 thread 0 zeroes acc
// (mark completes before gather starts -> visible).
__global__ __launch_bounds__(256) void vn_mark8(
    const int* __restrict__ p1x, const int* __restrict__ p1y,
    const int* __restrict__ p2x, const int* __restrict__ p2y,
    const int* __restrict__ p3x, const int* __restrict__ p3y,
    int G, unsigned char* __restrict__ mask8, double* __restrict__ acc)
{
    int g = blockIdx.x * 256 + threadIdx.x;
    if (blockIdx.x == 0 && threadIdx.x == 0) {
        acc[0] = 0.0;
        acc[1] = 0.0;
    }
    if (g >= G) return;
    mask8[p1y[g] * W_ + p1x[g]] = 1;
    mask8[p2y[g] * W_ + p2x[g]] = 1;
    mask8[p3y[g] * W_ + p3x[g]] = 1;
}

// ---------------- pack via LDS transpose, 256px tile, TOUCHED ONLY --------
// SoA 12B records (no pad):
//   recLo[pix*8+b] = uint2{ h2(gt0,gt1), h2(gt2,pr0) }   (8B)
//   recHi[pix*8+b] = uint  { h2(pr1,pr2) }               (4B)
// Phase 1: float4 coalesced plane reads (1KB/wave-inst) -> f16 LDS stage.
// Phase 2: predicated stores, lanes -> consecutive records (512B / 256B
// contiguous per wave-store-inst).
__global__ __launch_bounds__(256) void vn_pack_m(
    const float* __restrict__ gt, const float* __restrict__ pred,
    const unsigned char* __restrict__ mask8,
    uint2* __restrict__ recLo, unsigned int* __restrict__ recHi)
{
    __shared__ __half lh[48 * SEG_STRIDE];       // 24.96 KB
    __shared__ unsigned char lmask[256];

    size_t px_base = (size_t)blockIdx.x * 256;
    int t = threadIdx.x;
    int w = t >> 6, l = t & 63;

    if (t < 64)
        ((unsigned int*)lmask)[t] = ((const unsigned int*)(mask8 + px_base))[t];

    // phase 1: each wave loads 12 segments; one 1KB contiguous read per inst
    #pragma unroll
    for (int k = 0; k < 12; k++) {
        int s = w * 12 + k;              // s = b*6 + c
        int b = s / 6, c = s % 6;
        const float* src = (c < 3)
            ? gt   + ((size_t)b * 3 + c)       * HW_ + px_base
            : pred + ((size_t)b * 3 + (c - 3)) * HW_ + px_base;
        float4 v = *(const float4*)(src + l * 4);
        __half2 v01 = __floats2half2_rn(v.x, v.y);
        __half2 v23 = __floats2half2_rn(v.z, v.w);
        uint2 pk;
        pk.x = *(unsigned int*)&v01;
        pk.y = *(unsigned int*)&v23;
        *(uint2*)(&lh[(size_t)s * SEG_STRIDE + l * 4]) = pk;
    }

    __syncthreads();

    // phase 2: 8 records/thread; predicated contiguous wave stores
    int b  = t & 7;
    int c6 = b * 6;
    uint2*        outLo = recLo + px_base * 8;
    unsigned int* outHi = recHi + px_base * 8;
    #pragma unroll
    for (int r = 0; r < 8; r++) {
        int j    = t + r * 256;
        int i_px = j >> 3;               // [0,256)
        if (lmask[i_px]) {
            __half2 w0 = __halves2half2(lh[(c6 + 0) * SEG_STRIDE + i_px],
                                        lh[(c6 + 1) * SEG_STRIDE + i_px]);
            __half2 w1 = __halves2half2(lh[(c6 + 2) * SEG_STRIDE + i_px],
                                        lh[(c6 + 3) * SEG_STRIDE + i_px]);
            __half2 w2 = __halves2half2(lh[(c6 + 4) * SEG_STRIDE + i_px],
                                        lh[(c6 + 5) * SEG_STRIDE + i_px]);
            uint2 lo;
            lo.x = *(unsigned int*)&w0;
            lo.y = *(unsigned int*)&w1;
            outLo[j] = lo;
            outHi[j] = *(unsigned int*)&w2;
        }
    }
}

__device__ __forceinline__ void unpack_s(unsigned int lo0, unsigned int lo1,
                                         unsigned int hi, float G[3], float P[3])
{
    __half2 a = *(__half2*)&lo0;
    __half2 b = *(__half2*)&lo1;
    __half2 c = *(__half2*)&hi;
    G[0] = __low2float(a);  G[1] = __high2float(a);
    G[2] = __low2float(b);  P[0] = __high2float(b);
    P[1] = __low2float(c);  P[2] = __high2float(c);
}

// ---------------- gather: 2 threads per group, 4 batches each --------------
// Per point: 2x uint4 from recLo (32B, 16-aligned) + 1x uint4 from recHi
// (16B, 16-aligned) = 3 loads (vs 4 with AoS-16B records).
__global__ __launch_bounds__(256) void vn_gather_s(
    const uint2* __restrict__ recLo, const unsigned int* __restrict__ recHi,
    const int* __restrict__ p1x, const int* __restrict__ p1y,
    const int* __restrict__ p2x, const int* __restrict__ p2y,
    const int* __restrict__ p3x, const int* __restrict__ p3y,
    int G, double* __restrict__ acc)
{
    int t = blockIdx.x * 256 + threadIdx.x;
    int g = t >> 1;
    int h = (t & 1) * 4;          // batches [h, h+4)

    float s_loss = 0.f, s_cnt = 0.f;

    if (g < G) {
        size_t q1 = ((size_t)(p1y[g] * W_ + p1x[g])) * 8 + h;
        size_t q2 = ((size_t)(p2y[g] * W_ + p2x[g])) * 8 + h;
        size_t q3 = ((size_t)(p3y[g] * W_ + p3x[g])) * 8 + h;

        const uint4* L = (const uint4*)recLo;
        const uint4* H = (const uint4*)recHi;

        uint4 a1 = L[q1 >> 1], b1 = L[(q1 >> 1) + 1], h1 = H[q1 >> 2];
        uint4 a2 = L[q2 >> 1], b2 = L[(q2 >> 1) + 1], h2v = H[q2 >> 2];
        uint4 a3 = L[q3 >> 1], b3 = L[(q3 >> 1) + 1], h3 = H[q3 >> 2];

        unsigned int lo0_1[4] = {a1.x, a1.z, b1.x, b1.z};
        unsigned int lo1_1[4] = {a1.y, a1.w, b1.y, b1.w};
        unsigned int hi_1[4]  = {h1.x, h1.y, h1.z, h1.w};
        unsigned int lo0_2[4] = {a2.x, a2.z, b2.x, b2.z};
        unsigned int lo1_2[4] = {a2.y, a2.w, b2.y, b2.w};
        unsigned int hi_2[4]  = {h2v.x, h2v.y, h2v.z, h2v.w};
        unsigned int lo0_3[4] = {a3.x, a3.z, b3.x, b3.z};
        unsigned int lo1_3[4] = {a3.y, a3.w, b3.y, b3.w};
        unsigned int hi_3[4]  = {h3.x, h3.y, h3.z, h3.w};

        #pragma unroll
        for (int j = 0; j < 4; j++) {
            float G1[3], P1[3], G2[3], P2[3], G3[3], P3[3];
            unpack_s(lo0_1[j], lo1_1[j], hi_1[j], G1, P1);
            unpack_s(lo0_2[j], lo1_2[j], hi_2[j], G2, P2);
            unpack_s(lo0_3[j], lo1_3[j], hi_3[j], G3, P3);
            vn_group_math(G1, G2, G3, P1, P2, P3, s_loss, s_cnt);
        }
    }

    vn_reduce_store(s_loss, s_cnt, acc);
}

// ---------------- fallback: direct gather from plane-major (f32 exact) -----
__global__ __launch_bounds__(256) void vn_main(
    const float* __restrict__ gt, const float* __restrict__ pred,
    const int* __restrict__ p1x, const int* __restrict__ p1y,
    const int* __restrict__ p2x, const int* __restrict__ p2y,
    const int* __restrict__ p3x, const int* __restrict__ p3y,
    int G, double* __restrict__ acc)
{
    int g = blockIdx.x * 256 + threadIdx.x;
    int b = blockIdx.y;

    float s_loss = 0.f, s_cnt = 0.f;

    if (g < G) {
        int o1 = p1y[g] * W_ + p1x[g];
        int o2 = p2y[g] * W_ + p2x[g];
        int o3 = p3y[g] * W_ + p3x[g];
        const float* gb = gt   + (size_t)b * 3 * HW_;
        const float* pb = pred + (size_t)b * 3 * HW_;

        float G1[3], G2[3], G3[3], P1[3], P2[3], P3[3];
        #pragma unroll
        for (int c = 0; c < 3; c++) {
            G1[c] = gb[c * HW_ + o1];
            G2[c] = gb[c * HW_ + o2];
            G3[c] = gb[c * HW_ + o3];
            P1[c] = pb[c * HW_ + o1];
            P2[c] = pb[c * HW_ + o2];
            P3[c] = pb[c * HW_ + o3];
        }
        vn_group_math(G1, G2, G3, P1, P2, P3, s_loss, s_cnt);
    }

    vn_reduce_store(s_loss, s_cnt, acc);
}

__global__ void vn_final(const double* __restrict__ acc, float* __restrict__ out)
{
    float s = (float)acc[0];
    float c = (float)acc[1];
    out[0] = s / fmaxf(c, 1.0f);
}

extern "C" void kernel_launch(void* const* d_in, const int* in_sizes, int n_in,
                              void* d_out, int out_size, void* d_ws, size_t ws_size,
                              hipStream_t stream) {
    const float* gt   = (const float*)d_in[0];
    const float* pred = (const float*)d_in[1];
    const int* p1x = (const int*)d_in[2];
    const int* p1y = (const int*)d_in[3];
    const int* p2x = (const int*)d_in[4];
    const int* p2y = (const int*)d_in[5];
    const int* p3x = (const int*)d_in[6];
    const int* p3y = (const int*)d_in[7];

    int G = in_sizes[2];
    int B = in_sizes[0] / (3 * HW_);

    // ws layout: [0..16) acc doubles, [256..) byte mask (768KB),
    //            [1MB..) recLo (50.3MB), then recHi (25.2MB)
    double* acc = (double*)d_ws;

    size_t mask_off  = 256;
    size_t lo_off    = 1 << 20;
    size_t lo_bytes  = (size_t)HW_ * 8 * sizeof(uint2);       // 50.3 MB
    size_t hi_off    = lo_off + lo_bytes;
    size_t hi_bytes  = (size_t)HW_ * 8 * sizeof(unsigned int);// 25.2 MB
    size_t need = hi_off + hi_bytes;

    if (B == 8 && ws_size >= need) {
        unsigned char* mask8 = (unsigned char*)d_ws + mask_off;
        uint2*         recLo = (uint2*)((char*)d_ws + lo_off);
        unsigned int*  recHi = (unsigned int*)((char*)d_ws + hi_off);

        hipMemsetAsync(mask8, 0, HW_, stream);
        vn_mark8<<<(G + 255) / 256, 256, 0, stream>>>(
            p1x, p1y, p2x, p2y, p3x, p3y, G, mask8, acc);
        vn_pack_m<<<HW_ / 256, 256, 0, stream>>>(gt, pred, mask8, recLo, recHi);
        int nthreads = G * 2;                                 // 2 threads per group
        vn_gather_s<<<(nthreads + 255) / 256, 256, 0, stream>>>(
            recLo, recHi, p1x, p1y, p2x, p2y, p3x, p3y, G, acc);
    } else {
        hipMemsetAsync(acc, 0, 2 * sizeof(double), stream);
        dim3 grid((G + 255) / 256, B);
        vn_main<<<grid, 256, 0, stream>>>(gt, pred, p1x, p1y, p2x, p2y, p3x, p3y, G, acc);
    }

    vn_final<<<1, 1, 0, stream>>>(acc, (float*)d_out);
}